// Round 1
// baseline (154.134 us; speedup 1.0000x reference)
//
#include <hip/hip_runtime.h>
#include <math.h>

#define EPS 1e-7f

// Online softmax update: running max m, running sum s of exp(x - m).
// Branchy form: rescale only when the max changes (rare after warm-up),
// so ~1 v_exp_f32 per element instead of 2.
__device__ __forceinline__ void online_upd(float x, float& m, float& s) {
    if (x > m) {
        s *= __expf(m - x);   // first time: s==0, exp(-inf)=0 -> stays 0
        m = x;
    }
    s += __expf(x - m);
}

// One block per row. Computes max/sum-exp EXCLUDING the target column,
// then the loss for the row.
__global__ __launch_bounds__(256) void cml_row_kernel(
        const float* __restrict__ in, const int* __restrict__ target,
        float* __restrict__ row_loss, int C) {
    const int row = blockIdx.x;
    const int tid = threadIdx.x;
    const size_t base = (size_t)row * (size_t)C;
    const float* __restrict__ rowp = in + base;
    const int t = target[row];

    float m = -INFINITY;
    float s = 0.0f;

    // Row base alignment: base % 4 == row % 4 (C odd). Scalar prologue to
    // reach 16B alignment for float4 loads.
    const int mis = (int)(base & 3);
    const int pre = (4 - mis) & 3;
    if (tid < pre) {
        if (tid != t) online_upd(rowp[tid], m, s);
    }

    const int nv = (C - pre) >> 2;                 // number of aligned float4s
    const float4* __restrict__ v = reinterpret_cast<const float4*>(rowp + pre);
    for (int j = tid; j < nv; j += 256) {
        const float4 x4 = v[j];
        const int e = pre + (j << 2);
        if ((unsigned)(t - e) > 3u) {              // target not in this float4 (common case)
            online_upd(x4.x, m, s);
            online_upd(x4.y, m, s);
            online_upd(x4.z, m, s);
            online_upd(x4.w, m, s);
        } else {
            if (e + 0 != t) online_upd(x4.x, m, s);
            if (e + 1 != t) online_upd(x4.y, m, s);
            if (e + 2 != t) online_upd(x4.z, m, s);
            if (e + 3 != t) online_upd(x4.w, m, s);
        }
    }

    // Scalar tail
    for (int j = pre + (nv << 2) + tid; j < C; j += 256) {
        if (j != t) online_upd(rowp[j], m, s);
    }

    // Wave (64-lane) butterfly reduce of the (m, s) pair.
    #pragma unroll
    for (int off = 32; off > 0; off >>= 1) {
        const float mo = __shfl_xor(m, off, 64);
        const float so = __shfl_xor(s, off, 64);
        const float mn = fmaxf(m, mo);
        s = s * __expf(m - mn) + so * __expf(mo - mn);
        m = mn;
    }

    // Cross-wave combine via LDS (4 waves).
    __shared__ float sm[4];
    __shared__ float ss[4];
    if ((tid & 63) == 0) {
        sm[tid >> 6] = m;
        ss[tid >> 6] = s;
    }
    __syncthreads();

    if (tid == 0) {
        float M = sm[0], S = ss[0];
        #pragma unroll
        for (int w = 1; w < 4; ++w) {
            const float mo = sm[w], so = ss[w];
            const float mn = fmaxf(M, mo);
            S = S * __expf(M - mn) + so * __expf(mo - mn);
            M = mn;
        }
        // M = max over non-target columns, S = sum exp(x - M) over non-target.
        const float xt = rowp[t];
        const float mf = fmaxf(M, xt);               // full-row max
        const float Sf = S * __expf(M - mf) + __expf(xt - mf);
        const float p_t  = __expf(xt - mf) / Sf;     // prob of target class
        const float p_mi = __expf(M - mf) / Sf;      // max incorrect-class prob
        row_loss[row] = -logf(p_t + EPS) - logf(1.0f - p_mi + EPS);
    }
}

// Deterministic single-block mean of B per-row losses.
__global__ __launch_bounds__(256) void cml_mean_kernel(
        const float* __restrict__ row_loss, float* __restrict__ out, int B) {
    const int tid = threadIdx.x;
    float s = 0.0f;
    for (int i = tid; i < B; i += 256) s += row_loss[i];
    #pragma unroll
    for (int off = 32; off > 0; off >>= 1) s += __shfl_xor(s, off, 64);
    __shared__ float sw[4];
    if ((tid & 63) == 0) sw[tid >> 6] = s;
    __syncthreads();
    if (tid == 0) {
        out[0] = (sw[0] + sw[1] + sw[2] + sw[3]) / (float)B;
    }
}

extern "C" void kernel_launch(void* const* d_in, const int* in_sizes, int n_in,
                              void* d_out, int out_size, void* d_ws, size_t ws_size,
                              hipStream_t stream) {
    const float* in = (const float*)d_in[0];
    const int* target = (const int*)d_in[1];   // jax default: int32
    const int B = in_sizes[1];                 // 4096
    const int C = in_sizes[0] / B;             // 50257
    float* row_loss = (float*)d_ws;            // B floats of scratch

    cml_row_kernel<<<B, 256, 0, stream>>>(in, target, row_loss, C);
    cml_mean_kernel<<<1, 256, 0, stream>>>(row_loss, (float*)d_out, B);
}

// Round 3
// 141.130 us; speedup vs baseline: 1.0921x; 1.0921x over previous
//
#include <hip/hip_runtime.h>
#include <math.h>

#define EPS 1e-7f

// Native clang vector type — required for __builtin_nontemporal_load.
typedef float f32x4 __attribute__((ext_vector_type(4)));

// Scalar online-softmax update (used only in rare/edge paths).
__device__ __forceinline__ void online_upd(float x, float& m, float& s) {
    if (x > m) {
        s *= __expf(m - x);
        m = x;
    }
    s += __expf(x - m);
}

// Amortized float4 update: ONE max-compare per 4 elements, 4 independent
// exps, tree-summed (serial chain = 1 add per float4 instead of 4).
// e = element index of x4[0]; t = target column (excluded per-element only
// when it falls inside this float4 — at most once per row).
__device__ __forceinline__ void upd4(const f32x4 x4, int e, int t,
                                     float& m, float& s) {
    if ((unsigned)(t - e) > 3u) {          // common case: target not here
        const float lm = fmaxf(fmaxf(x4.x, x4.y), fmaxf(x4.z, x4.w));
        if (lm > m) {
            s *= __expf(m - lm);           // s==0 first time: exp(-inf)=0 ok
            m = lm;
        }
        const float e0 = __expf(x4.x - m);
        const float e1 = __expf(x4.y - m);
        const float e2 = __expf(x4.z - m);
        const float e3 = __expf(x4.w - m);
        s += (e0 + e1) + (e2 + e3);
    } else {                               // rare: exclude target element
        if (e + 0 != t) online_upd(x4.x, m, s);
        if (e + 1 != t) online_upd(x4.y, m, s);
        if (e + 2 != t) online_upd(x4.z, m, s);
        if (e + 3 != t) online_upd(x4.w, m, s);
    }
}

// Merge (mo, so) into (m, s).
__device__ __forceinline__ void merge(float mo, float so, float& m, float& s) {
    const float mn = fmaxf(m, mo);
    s = s * __expf(m - mn) + so * __expf(mo - mn);
    m = mn;
}

// One block per row: max & sum-exp EXCLUDING target column, then row loss.
__global__ __launch_bounds__(256) void cml_row_kernel(
        const float* __restrict__ in, const int* __restrict__ target,
        float* __restrict__ row_loss, int C) {
    const int row = blockIdx.x;
    const int tid = threadIdx.x;
    const size_t base = (size_t)row * (size_t)C;
    const float* __restrict__ rowp = in + base;
    const int t = target[row];

    float m0 = -INFINITY, s0 = 0.0f;
    float m1 = -INFINITY, s1 = 0.0f;

    // Scalar prologue to 16B alignment (base % 4 == row % 4, C odd).
    const int pre = (4 - (int)(base & 3)) & 3;
    if (tid < pre) {
        if (tid != t) online_upd(rowp[tid], m0, s0);
    }

    const int nv = (C - pre) >> 2;  // aligned float4 count
    const f32x4* __restrict__ v = reinterpret_cast<const f32x4*>(rowp + pre);

    // Unroll-2 with two independent accumulator pairs (ILP on the s-chain).
    int j = tid;
    for (; j + 256 < nv; j += 512) {
        const f32x4 a = __builtin_nontemporal_load(&v[j]);
        const f32x4 b = __builtin_nontemporal_load(&v[j + 256]);
        upd4(a, pre + (j << 2),           t, m0, s0);
        upd4(b, pre + ((j + 256) << 2),   t, m1, s1);
    }
    if (j < nv) {
        const f32x4 a = __builtin_nontemporal_load(&v[j]);
        upd4(a, pre + (j << 2), t, m0, s0);
    }

    // Scalar tail.
    for (int k = pre + (nv << 2) + tid; k < C; k += 256) {
        if (k != t) online_upd(rowp[k], m0, s0);
    }

    // Merge the two accumulators. merge() handles s==0 via exp(-inf)=0 as
    // long as at least one m is finite — true for every thread here.
    merge(m1, s1, m0, s0);

    // Wave butterfly reduce of (m0, s0).
    #pragma unroll
    for (int off = 32; off > 0; off >>= 1) {
        const float mo = __shfl_xor(m0, off, 64);
        const float so = __shfl_xor(s0, off, 64);
        merge(mo, so, m0, s0);
    }

    // Cross-wave combine via LDS (4 waves).
    __shared__ float sm[4];
    __shared__ float ss[4];
    if ((tid & 63) == 0) {
        sm[tid >> 6] = m0;
        ss[tid >> 6] = s0;
    }
    __syncthreads();

    if (tid == 0) {
        float M = sm[0], S = ss[0];
        #pragma unroll
        for (int w = 1; w < 4; ++w) merge(sm[w], ss[w], M, S);
        // M = max over non-target, S = sum exp(x - M) over non-target.
        const float xt = rowp[t];
        const float mf = fmaxf(M, xt);
        const float Sf = S * __expf(M - mf) + __expf(xt - mf);
        const float p_t  = __expf(xt - mf) / Sf;
        const float p_mi = __expf(M - mf) / Sf;
        row_loss[row] = -logf(p_t + EPS) - logf(1.0f - p_mi + EPS);
    }
}

// Deterministic single-block mean of B per-row losses.
__global__ __launch_bounds__(256) void cml_mean_kernel(
        const float* __restrict__ row_loss, float* __restrict__ out, int B) {
    const int tid = threadIdx.x;
    float s = 0.0f;
    for (int i = tid; i < B; i += 256) s += row_loss[i];
    #pragma unroll
    for (int off = 32; off > 0; off >>= 1) s += __shfl_xor(s, off, 64);
    __shared__ float sw[4];
    if ((tid & 63) == 0) sw[tid >> 6] = s;
    __syncthreads();
    if (tid == 0) {
        out[0] = (sw[0] + sw[1] + sw[2] + sw[3]) / (float)B;
    }
}

extern "C" void kernel_launch(void* const* d_in, const int* in_sizes, int n_in,
                              void* d_out, int out_size, void* d_ws, size_t ws_size,
                              hipStream_t stream) {
    const float* in = (const float*)d_in[0];
    const int* target = (const int*)d_in[1];
    const int B = in_sizes[1];                 // 4096
    const int C = in_sizes[0] / B;             // 50257
    float* row_loss = (float*)d_ws;            // B floats of scratch

    cml_row_kernel<<<B, 256, 0, stream>>>(in, target, row_loss, C);
    cml_mean_kernel<<<1, 256, 0, stream>>>(row_loss, (float*)d_out, B);
}